// Round 1
// baseline (304.181 us; speedup 1.0000x reference)
//
#include <hip/hip_runtime.h>
#include <stdint.h>

// Self-attention, B=8 S=2048 D=E=512, fp32 in/out, bf16 MFMA internally.
//   xconv:    x fp32 -> bf16
//   wconv:    W[k][n] fp32 -> Wt[n][k] bf16 (x3)
//   qkv_gemm: m97-style async-staged GEMM; Q,K row-major bf16; V transposed [B,E,S] bf16
//   attn:     flash (no-max softmax), 32 Q-rows/block, 512 blocks, 2 blocks/CU.
//             v2: V fragments load global->reg (L2-resident; deletes V LDS round-trip),
//             Kt double-buffered (full-iter DMA window), Pl double-buffered,
//             ONE barrier/iter, Pl stride 40 (conflict-free b128 reads).

using f32x4 = __attribute__((ext_vector_type(4))) float;
using s16x8 = __attribute__((ext_vector_type(8))) short;
using u16x4 = __attribute__((ext_vector_type(4))) unsigned short;

#define S_LEN 2048
#define EMB   512

#define ASYNC16(g, l)                                                     \
  __builtin_amdgcn_global_load_lds(                                       \
      (const __attribute__((address_space(1))) void*)(g),                 \
      (__attribute__((address_space(3))) void*)(l), 16, 0, 0)

__device__ __forceinline__ unsigned short f2bf(float f) {
  union { float f; unsigned u; } v; v.f = f;
  unsigned r = v.u + 0x7fffu + ((v.u >> 16) & 1u);   // RNE
  return (unsigned short)(r >> 16);
}

// ---------------- kernel 0: x fp32 -> bf16 ----------------
__global__ __launch_bounds__(256) void xconv_kernel(
    const float* __restrict__ x, short* __restrict__ xb) {
  int i = (blockIdx.x * 256 + threadIdx.x) * 8;
  f32x4 a = *(const f32x4*)(x + i);
  f32x4 b = *(const f32x4*)(x + i + 4);
  s16x8 h;
  h[0] = (short)f2bf(a[0]); h[1] = (short)f2bf(a[1]);
  h[2] = (short)f2bf(a[2]); h[3] = (short)f2bf(a[3]);
  h[4] = (short)f2bf(b[0]); h[5] = (short)f2bf(b[1]);
  h[6] = (short)f2bf(b[2]); h[7] = (short)f2bf(b[3]);
  *(s16x8*)(xb + i) = h;
}

// ---------------- kernel 1: weight transpose + convert ----------------
__global__ __launch_bounds__(256) void wconv_kernel(
    const float* __restrict__ Wq, const float* __restrict__ Wk,
    const float* __restrict__ Wv, short* __restrict__ Wt) {
  int idx = blockIdx.x * 256 + threadIdx.x;
  int mat = idx >> 18;
  int r   = idx & 262143;
  int n   = r >> 9;
  int k   = r & 511;
  const float* W = (mat == 0) ? Wq : (mat == 1) ? Wk : Wv;
  Wt[idx] = (short)f2bf(W[k * 512 + n]);
}

// ---------------- kernel 2: QKV projection GEMM (m97 structure) ----------------
__global__ __launch_bounds__(256) void qkv_gemm(
    const short* __restrict__ xb, const short* __restrict__ Wt,
    const float* __restrict__ bq, const float* __restrict__ bk,
    const float* __restrict__ bv,
    short* __restrict__ Qg, short* __restrict__ Kg, short* __restrict__ VTg) {
  __shared__ __align__(16) short As[128 * 64];   // 16B chunk c stored at c^(row&7)
  __shared__ __align__(16) short Bs[128 * 64];
  int gid = blockIdx.x;
  int mat = gid >> 9;
  int rem = gid & 511;
  int mt  = rem & 127, nt = rem >> 7;
  int m0  = mt << 7,   n0 = nt << 7;
  const short* W    = Wt + (size_t)mat * 262144;
  const float* bias = (mat == 0) ? bq : (mat == 1) ? bk : bv;

  int tid = threadIdx.x, lane = tid & 63, wv = tid >> 6;
  int l16 = lane & 15, quad = lane >> 4;
  int wr = (wv & 1) << 6, wc = (wv >> 1) << 6;
  int drow = lane >> 3;
  int dchk = (lane & 7) ^ drow;

  const f32x4 Z4 = {0.f, 0.f, 0.f, 0.f};
  f32x4 acc[4][4];
#pragma unroll
  for (int a = 0; a < 4; ++a)
#pragma unroll
    for (int c = 0; c < 4; ++c) acc[a][c] = Z4;

  for (int it = 0; it < 8; ++it) {
    int k0 = it << 6;
    __syncthreads();
#pragma unroll
    for (int i = 0; i < 4; ++i) {
      int g   = wv * 4 + i;
      int row = g * 8 + drow;
      ASYNC16(xb + (size_t)(m0 + row) * 512 + k0 + dchk * 8, &As[g * 512]);
    }
#pragma unroll
    for (int i = 0; i < 4; ++i) {
      int g   = wv * 4 + i;
      int row = g * 8 + drow;
      ASYNC16(W + (size_t)(n0 + row) * 512 + k0 + dchk * 8, &Bs[g * 512]);
    }
    __syncthreads();
#pragma unroll
    for (int kk = 0; kk < 2; ++kk) {
      s16x8 af[4], bfr[4];
#pragma unroll
      for (int rb = 0; rb < 4; ++rb) {
        int row = wr + rb * 16 + l16;
        int c   = kk * 4 + quad;
        af[rb] = *(const s16x8*)(As + row * 64 + ((c ^ (row & 7)) * 8));
      }
#pragma unroll
      for (int cb = 0; cb < 4; ++cb) {
        int row = wc + cb * 16 + l16;
        int c   = kk * 4 + quad;
        bfr[cb] = *(const s16x8*)(Bs + row * 64 + ((c ^ (row & 7)) * 8));
      }
#pragma unroll
      for (int rb = 0; rb < 4; ++rb)
#pragma unroll
        for (int cb = 0; cb < 4; ++cb)
          acc[rb][cb] = __builtin_amdgcn_mfma_f32_16x16x32_bf16(af[rb], bfr[cb], acc[rb][cb], 0, 0, 0);
    }
  }

  float bsv[4];
#pragma unroll
  for (int cb = 0; cb < 4; ++cb) bsv[cb] = bias[n0 + wc + cb * 16 + l16];

  if (mat < 2) {
    short* D = (mat == 0) ? Qg : Kg;
#pragma unroll
    for (int rb = 0; rb < 4; ++rb)
#pragma unroll
      for (int cb = 0; cb < 4; ++cb)
#pragma unroll
        for (int r = 0; r < 4; ++r) {
          int m = m0 + wr + rb * 16 + quad * 4 + r;
          D[(size_t)m * 512 + n0 + wc + cb * 16 + l16] =
              (short)f2bf(acc[rb][cb][r] + bsv[cb]);
        }
  } else {
#pragma unroll
    for (int rb = 0; rb < 4; ++rb)
#pragma unroll
      for (int cb = 0; cb < 4; ++cb) {
        u16x4 h;
#pragma unroll
        for (int r = 0; r < 4; ++r) h[r] = f2bf(acc[rb][cb][r] + bsv[cb]);
        int m  = m0 + wr + rb * 16 + quad * 4;
        int bb = m >> 11, s = m & 2047;
        int e  = n0 + wc + cb * 16 + l16;
        *(u16x4*)(VTg + ((size_t)bb * 512 + e) * 2048 + s) = h;
      }
  }
}

// ---------------- kernel 3: flash attention v2 ----------------
// grid = 512 blocks (b = blk&7 -> XCD L2 pinning), 32 Q-rows/block, 4 waves,
// ~70 KB LDS -> 2 blocks/CU.  V frags global->reg (no V LDS round-trip).
// Kt & Pl double-buffered -> ONE barrier per 32-key iteration.
// Hazard ledger (all separated by the single per-iter barrier):
//   P-write(kt)   [pre-barrier kt]  -> P-read(kt)     [post-barrier kt]
//   P-read(kt-1)  [pre-barrier kt]  -> P-write(kt+1)  [post-barrier kt]
//   Kt[c] reads QK(kt) [pre-b kt]   -> DMA(kt+2)->Kt[c] [post-b kt]
//   DMA(kt+1) issued [post-b kt-1]  -> drained by vmcnt(0) at barrier kt -> QK(kt+1)
__global__ __launch_bounds__(256, 2) void attn_kernel(
    const short* __restrict__ Qg, const short* __restrict__ Kg,
    const short* __restrict__ VTg, float* __restrict__ out) {
  __shared__ __align__(16) short Kt[2][32 * 512];   // 64 KB, [buf][key][chunk^(key&7)]
  __shared__ __align__(16) short Pl[2][32 * 40];    // 5 KB, row stride 40 shorts (80 B)
  __shared__ float l_l[32];
  const float SCL2 = 0.06375871855f;  // log2(e)/sqrt(512)

  int b = blockIdx.x & 7, qt = blockIdx.x >> 3;
  int s0 = qt << 5;
  int tid = threadIdx.x, lane = tid & 63, wv = tid >> 6;
  int l16 = lane & 15, quad = lane >> 4;
  int a = wv & 1, h = wv >> 1;
  int e0 = wv << 7;

  const short* Kb = Kg  + ((size_t)b * S_LEN) * 512;
  const short* Vb = VTg + ((size_t)b * 512) * 2048;

  // K DMA per-lane source addresses (one row of 512 shorts per op, chunk-swizzled)
  const short* kdma[8];
#pragma unroll
  for (int i = 0; i < 8; ++i) {
    int r = wv * 8 + i;
    kdma[i] = Kb + (size_t)r * 512 + ((lane ^ (i & 7)) * 8);
  }
  // V fragment per-lane base: frag cb at +cb*32768 shorts, key-tile kt at +kt*32
  const short* vbase = Vb + (size_t)(e0 + l16) * 2048 + quad * 8;

  // ---- prologue: stage K tiles 0 and 1, load Q frags ----
#pragma unroll
  for (int i = 0; i < 8; ++i)
    ASYNC16(kdma[i], &Kt[0][(wv * 8 + i) * 512]);
#pragma unroll
  for (int i = 0; i < 8; ++i)
    ASYNC16(kdma[i] + 16384, &Kt[1][(wv * 8 + i) * 512]);

  const short* qrow = Qg + ((size_t)b * S_LEN + s0 + a * 16 + l16) * 512 + quad * 8;
  s16x8 qf[16];
#pragma unroll
  for (int kk = 0; kk < 16; ++kk) qf[kk] = *(const s16x8*)(qrow + kk * 32);

  const f32x4 Z4 = {0.f, 0.f, 0.f, 0.f};
  f32x4 acc[2][8];
#pragma unroll
  for (int rb = 0; rb < 2; ++rb)
#pragma unroll
    for (int cb = 0; cb < 8; ++cb) acc[rb][cb] = Z4;
  f32x4 lsum = Z4;                 // per-lane partial row sums

  __syncthreads();                 // K tiles 0,1 + Q frags drained

  for (int kt = 0; kt < 64; ++kt) {
    int cur = kt & 1;
    int t0  = kt << 5;

    // ---- V frag loads (global, L2-resident); consumed in PV after the barrier ----
    s16x8 vf[8];
#pragma unroll
    for (int cb = 0; cb < 8; ++cb)
      vf[cb] = *(const s16x8*)(vbase + cb * 32768 + t0);

    // ---- QK: S[16 rows(a) x 16 keys(h)] ; two independent MFMA chains ----
    f32x4 s_a = Z4, s_b = Z4;
    int krow = h * 16 + l16;
    const short* kb = &Kt[cur][krow * 512];
    int ksw = krow & 7;
#pragma unroll
    for (int kk = 0; kk < 8; ++kk) {
      s16x8 kf0 = *(const s16x8*)(kb + (((2 * kk) * 4 + quad) ^ ksw) * 8);
      s_a = __builtin_amdgcn_mfma_f32_16x16x32_bf16(qf[2 * kk], kf0, s_a, 0, 0, 0);
      s16x8 kf1 = *(const s16x8*)(kb + (((2 * kk + 1) * 4 + quad) ^ ksw) * 8);
      s_b = __builtin_amdgcn_mfma_f32_16x16x32_bf16(qf[2 * kk + 1], kf1, s_b, 0, 0, 0);
    }
    f32x4 sv = s_a + s_b;

    // ---- no-max softmax: p = exp2(s*SCL2); write P to Pl[cur] ----
#pragma unroll
    for (int r = 0; r < 4; ++r) {
      float p = exp2f(sv[r] * SCL2);
      lsum[r] += p;
      Pl[cur][(a * 16 + quad * 4 + r) * 40 + h * 16 + l16] = (short)f2bf(p);
    }

    __syncthreads();   // single per-iter barrier (drains vmcnt: V frags + DMA(kt+1))

    // ---- stage K tile kt+2 into Kt[cur] (its readers just finished) ----
    if (kt + 2 < 64) {
      size_t adv = (size_t)(kt + 2) * 16384;
#pragma unroll
      for (int i = 0; i < 8; ++i)
        ASYNC16(kdma[i] + adv, &Kt[cur][(wv * 8 + i) * 512]);
    }

    // ---- PV: O[32 x 128chunk] += P[32x32] @ V[32 x 128chunk] ----
    s16x8 pf[2];
#pragma unroll
    for (int rb = 0; rb < 2; ++rb)
      pf[rb] = *(const s16x8*)(&Pl[cur][(rb * 16 + l16) * 40 + quad * 8]);
#pragma unroll
    for (int cb = 0; cb < 8; ++cb)
#pragma unroll
      for (int rb = 0; rb < 2; ++rb)
        acc[rb][cb] = __builtin_amdgcn_mfma_f32_16x16x32_bf16(pf[rb], vf[cb], acc[rb][cb], 0, 0, 0);
    // no second barrier: Pl is double-buffered; Kt[cur^1] was drained at this
    // iter's barrier; next iter's P-writes go to Pl[cur^1] whose readers
    // (PV of kt-1) are behind this iter's barrier.
  }

  // ---- epilogue: combine row sums, divide, store fp32 ----
#pragma unroll
  for (int r = 0; r < 4; ++r) {
    float v = lsum[r];
    v += __shfl_xor(v, 1);
    v += __shfl_xor(v, 2);
    v += __shfl_xor(v, 4);
    v += __shfl_xor(v, 8);
    lsum[r] = v;                    // full sum over this wave's 16-key half
  }
  if (h == 0 && l16 == 0) {
#pragma unroll
    for (int r = 0; r < 4; ++r) l_l[a * 16 + quad * 4 + r] = lsum[r];
  }
  __syncthreads();
  if (h == 1 && l16 == 0) {
#pragma unroll
    for (int r = 0; r < 4; ++r) l_l[a * 16 + quad * 4 + r] += lsum[r];
  }
  __syncthreads();

#pragma unroll
  for (int rb = 0; rb < 2; ++rb) {
    f32x4 lv = *(const f32x4*)(l_l + rb * 16 + quad * 4);
    f32x4 li;
#pragma unroll
    for (int r = 0; r < 4; ++r) li[r] = 1.0f / lv[r];
#pragma unroll
    for (int cb = 0; cb < 8; ++cb)
#pragma unroll
      for (int r = 0; r < 4; ++r)
        out[((size_t)b * S_LEN + s0 + rb * 16 + quad * 4 + r) * 512 + e0 + cb * 16 + l16] =
            acc[rb][cb][r] * li[r];
  }
}

// ---------------- host launch ----------------
extern "C" void kernel_launch(void* const* d_in, const int* in_sizes, int n_in,
                              void* d_out, int out_size, void* d_ws, size_t ws_size,
                              hipStream_t stream) {
  const float* x  = (const float*)d_in[0];
  const float* Wq = (const float*)d_in[1];
  const float* bq = (const float*)d_in[2];
  const float* Wk = (const float*)d_in[3];
  const float* bk = (const float*)d_in[4];
  const float* Wv = (const float*)d_in[5];
  const float* bv = (const float*)d_in[6];

  short* Wt  = (short*)d_ws;
  short* xb  = (short*)((char*)d_ws + 1572864);
  short* Qg  = xb + (size_t)8388608;
  short* Kg  = Qg + (size_t)8388608;
  short* VTg = Kg + (size_t)8388608;

  xconv_kernel<<<4096, 256, 0, stream>>>(x, xb);
  wconv_kernel<<<3072, 256, 0, stream>>>(Wq, Wk, Wv, Wt);
  qkv_gemm<<<1536, 256, 0, stream>>>(xb, Wt, bq, bk, bv, Qg, Kg, VTg);
  attn_kernel<<<512, 256, 0, stream>>>(Qg, Kg, VTg, (float*)d_out);
}

// Round 2
// 241.069 us; speedup vs baseline: 1.2618x; 1.2618x over previous
//
#include <hip/hip_runtime.h>
#include <stdint.h>

// Self-attention, B=8 S=2048 D=E=512, fp32 in/out, bf16 MFMA internally.
//   xconv:    x fp32 -> bf16
//   wconv:    W[k][n] fp32 -> Wt[n][k] bf16 (x3)
//   qkv_gemm: m97-style async-staged GEMM; Q,K row-major bf16; V in 16e x 32s
//             1KB-tiled transposed layout [B][E/16][S/32][16][32] bf16
//   attn:     flash (no-max softmax), v3: 64 Q-rows/block, 8 waves, 256 blocks
//             (1/CU, b=blk&7 XCD-pins K/V; halves per-XCD L2 traffic vs v1),
//             v1-proven 2-barrier ledger, single Kt buffer, V global->reg
//             with perfectly-coalesced 1KB tile loads.

using f32x4 = __attribute__((ext_vector_type(4))) float;
using s16x8 = __attribute__((ext_vector_type(8))) short;
using u16x4 = __attribute__((ext_vector_type(4))) unsigned short;

#define S_LEN 2048
#define EMB   512

#define ASYNC16(g, l)                                                     \
  __builtin_amdgcn_global_load_lds(                                       \
      (const __attribute__((address_space(1))) void*)(g),                 \
      (__attribute__((address_space(3))) void*)(l), 16, 0, 0)

__device__ __forceinline__ unsigned short f2bf(float f) {
  union { float f; unsigned u; } v; v.f = f;
  unsigned r = v.u + 0x7fffu + ((v.u >> 16) & 1u);   // RNE
  return (unsigned short)(r >> 16);
}

// ---------------- kernel 0: x fp32 -> bf16 ----------------
__global__ __launch_bounds__(256) void xconv_kernel(
    const float* __restrict__ x, short* __restrict__ xb) {
  int i = (blockIdx.x * 256 + threadIdx.x) * 8;
  f32x4 a = *(const f32x4*)(x + i);
  f32x4 b = *(const f32x4*)(x + i + 4);
  s16x8 h;
  h[0] = (short)f2bf(a[0]); h[1] = (short)f2bf(a[1]);
  h[2] = (short)f2bf(a[2]); h[3] = (short)f2bf(a[3]);
  h[4] = (short)f2bf(b[0]); h[5] = (short)f2bf(b[1]);
  h[6] = (short)f2bf(b[2]); h[7] = (short)f2bf(b[3]);
  *(s16x8*)(xb + i) = h;
}

// ---------------- kernel 1: weight transpose + convert ----------------
__global__ __launch_bounds__(256) void wconv_kernel(
    const float* __restrict__ Wq, const float* __restrict__ Wk,
    const float* __restrict__ Wv, short* __restrict__ Wt) {
  int idx = blockIdx.x * 256 + threadIdx.x;
  int mat = idx >> 18;
  int r   = idx & 262143;
  int n   = r >> 9;
  int k   = r & 511;
  const float* W = (mat == 0) ? Wq : (mat == 1) ? Wk : Wv;
  Wt[idx] = (short)f2bf(W[k * 512 + n]);
}

// ---------------- kernel 2: QKV projection GEMM (m97 structure) ----------------
__global__ __launch_bounds__(256) void qkv_gemm(
    const short* __restrict__ xb, const short* __restrict__ Wt,
    const float* __restrict__ bq, const float* __restrict__ bk,
    const float* __restrict__ bv,
    short* __restrict__ Qg, short* __restrict__ Kg, short* __restrict__ VTg) {
  __shared__ __align__(16) short As[128 * 64];   // 16B chunk c stored at c^(row&7)
  __shared__ __align__(16) short Bs[128 * 64];
  int gid = blockIdx.x;
  int mat = gid >> 9;
  int rem = gid & 511;
  int mt  = rem & 127, nt = rem >> 7;
  int m0  = mt << 7,   n0 = nt << 7;
  const short* W    = Wt + (size_t)mat * 262144;
  const float* bias = (mat == 0) ? bq : (mat == 1) ? bk : bv;

  int tid = threadIdx.x, lane = tid & 63, wv = tid >> 6;
  int l16 = lane & 15, quad = lane >> 4;
  int wr = (wv & 1) << 6, wc = (wv >> 1) << 6;
  int drow = lane >> 3;
  int dchk = (lane & 7) ^ drow;

  const f32x4 Z4 = {0.f, 0.f, 0.f, 0.f};
  f32x4 acc[4][4];
#pragma unroll
  for (int a = 0; a < 4; ++a)
#pragma unroll
    for (int c = 0; c < 4; ++c) acc[a][c] = Z4;

  for (int it = 0; it < 8; ++it) {
    int k0 = it << 6;
    __syncthreads();
#pragma unroll
    for (int i = 0; i < 4; ++i) {
      int g   = wv * 4 + i;
      int row = g * 8 + drow;
      ASYNC16(xb + (size_t)(m0 + row) * 512 + k0 + dchk * 8, &As[g * 512]);
    }
#pragma unroll
    for (int i = 0; i < 4; ++i) {
      int g   = wv * 4 + i;
      int row = g * 8 + drow;
      ASYNC16(W + (size_t)(n0 + row) * 512 + k0 + dchk * 8, &Bs[g * 512]);
    }
    __syncthreads();
#pragma unroll
    for (int kk = 0; kk < 2; ++kk) {
      s16x8 af[4], bfr[4];
#pragma unroll
      for (int rb = 0; rb < 4; ++rb) {
        int row = wr + rb * 16 + l16;
        int c   = kk * 4 + quad;
        af[rb] = *(const s16x8*)(As + row * 64 + ((c ^ (row & 7)) * 8));
      }
#pragma unroll
      for (int cb = 0; cb < 4; ++cb) {
        int row = wc + cb * 16 + l16;
        int c   = kk * 4 + quad;
        bfr[cb] = *(const s16x8*)(Bs + row * 64 + ((c ^ (row & 7)) * 8));
      }
#pragma unroll
      for (int rb = 0; rb < 4; ++rb)
#pragma unroll
        for (int cb = 0; cb < 4; ++cb)
          acc[rb][cb] = __builtin_amdgcn_mfma_f32_16x16x32_bf16(af[rb], bfr[cb], acc[rb][cb], 0, 0, 0);
    }
  }

  float bsv[4];
#pragma unroll
  for (int cb = 0; cb < 4; ++cb) bsv[cb] = bias[n0 + wc + cb * 16 + l16];

  if (mat < 2) {
    short* D = (mat == 0) ? Qg : Kg;
#pragma unroll
    for (int rb = 0; rb < 4; ++rb)
#pragma unroll
      for (int cb = 0; cb < 4; ++cb)
#pragma unroll
        for (int r = 0; r < 4; ++r) {
          int m = m0 + wr + rb * 16 + quad * 4 + r;
          D[(size_t)m * 512 + n0 + wc + cb * 16 + l16] =
              (short)f2bf(acc[rb][cb][r] + bsv[cb]);
        }
  } else {
    // V: tiled transpose layout [bb][e>>4][s>>5][e&15][s&31], 1KB tiles
#pragma unroll
    for (int rb = 0; rb < 4; ++rb)
#pragma unroll
      for (int cb = 0; cb < 4; ++cb) {
        u16x4 h;
#pragma unroll
        for (int r = 0; r < 4; ++r) h[r] = f2bf(acc[rb][cb][r] + bsv[cb]);
        int m  = m0 + wr + rb * 16 + quad * 4;
        int bb = m >> 11, s = m & 2047;
        int e  = n0 + wc + cb * 16 + l16;
        size_t idx = ((((size_t)bb * 32 + (e >> 4)) * 64 + (s >> 5)) * 16 +
                      (e & 15)) * 32 + (s & 31);
        *(u16x4*)(VTg + idx) = h;
      }
  }
}

// ---------------- kernel 3: flash attention v3 ----------------
// 256 blocks (b=blk&7 -> XCD; 32 blocks/XCD, 1 block/CU), 64 Q-rows/block,
// 8 waves: QK wave (a=wv&3: 16-row group, h=wv>>2: 16-key half);
//          PV wave owns e-slice e0=wv*64.
// LDS 38 KB: Kt 32 KB (single buffer, XOR-swizzled rows), Pl 64x40, l_l.
// v1-proven 2-barrier ledger:
//   Vload(kt) issue -> QK(kt) reads Kt -> softmax -> Pl write
//   B1 [drains Vloads; Kt reads done; P visible]
//   K-DMA(kt+1) -> Kt ; PV(kt) reads Pl + vf regs
//   B2 [drains K-DMA; Pl WAR protected]
__global__ __launch_bounds__(512, 2) void attn_kernel(
    const short* __restrict__ Qg, const short* __restrict__ Kg,
    const short* __restrict__ VTg, float* __restrict__ out) {
  __shared__ __align__(16) short Kt[32 * 512];   // 32 KB, [key][chunk^(key&7)]
  __shared__ __align__(16) short Pl[64 * 40];    // 5 KB, stride 40 shorts (80 B)
  __shared__ float l_l[64];
  const float SCL2 = 0.06375871855f;  // log2(e)/sqrt(512)

  int b = blockIdx.x & 7, qt = blockIdx.x >> 3;   // qt 0..31
  int s0 = qt << 6;                                // 64 rows/block
  int tid = threadIdx.x, lane = tid & 63, wv = tid >> 6;  // wv 0..7
  int l16 = lane & 15, quad = lane >> 4;
  int a = wv & 3, h = wv >> 2;
  int e0 = wv << 6;                                // 64-wide e slice

  const short* Kb = Kg  + (size_t)b * S_LEN * 512;
  const short* Vb = VTg + (size_t)b * 1048576;     // [32 et][64 st][16][32]

  // K DMA per-lane source addresses (1 row = 1KB per op, chunk-swizzled src)
  const short* kdma[4];
#pragma unroll
  for (int i = 0; i < 4; ++i) {
    int r = wv * 4 + i;
    kdma[i] = Kb + (size_t)r * 512 + ((lane ^ (r & 7)) * 8);
  }
  // V fragment base: tile (et = wv*4+cb, st = kt), lane offset l16*32+quad*8
  // -> each vf load is a fully-coalesced 1KB wave access.
  const short* vbase = Vb + (size_t)wv * 131072 + l16 * 32 + quad * 8;

  // ---- prologue: stage K tile 0, load Q frags ----
#pragma unroll
  for (int i = 0; i < 4; ++i)
    ASYNC16(kdma[i], &Kt[(wv * 4 + i) * 512]);

  const short* qrow = Qg + ((size_t)b * S_LEN + s0 + a * 16 + l16) * 512 + quad * 8;
  s16x8 qf[16];
#pragma unroll
  for (int kk = 0; kk < 16; ++kk) qf[kk] = *(const s16x8*)(qrow + kk * 32);

  const f32x4 Z4 = {0.f, 0.f, 0.f, 0.f};
  f32x4 acc[4][4];
#pragma unroll
  for (int rb = 0; rb < 4; ++rb)
#pragma unroll
    for (int cb = 0; cb < 4; ++cb) acc[rb][cb] = Z4;
  f32x4 lsum = Z4;

  __syncthreads();   // K tile 0 + Q frags drained

  for (int kt = 0; kt < 64; ++kt) {
    // ---- V frag loads (global->reg, coalesced 1KB/wave); used in PV ----
    s16x8 vf[4];
#pragma unroll
    for (int cb = 0; cb < 4; ++cb)
      vf[cb] = *(const s16x8*)(vbase + cb * 32768 + kt * 512);

    // ---- QK: S[16 rows(a) x 16 keys(h)] ----
    f32x4 s_a = Z4, s_b = Z4;
    int krow = h * 16 + l16;
    const short* kb = &Kt[krow * 512];
    int ksw = krow & 7;
#pragma unroll
    for (int kk = 0; kk < 8; ++kk) {
      s16x8 kf0 = *(const s16x8*)(kb + (((2 * kk) * 4 + quad) ^ ksw) * 8);
      s_a = __builtin_amdgcn_mfma_f32_16x16x32_bf16(qf[2 * kk], kf0, s_a, 0, 0, 0);
      s16x8 kf1 = *(const s16x8*)(kb + (((2 * kk + 1) * 4 + quad) ^ ksw) * 8);
      s_b = __builtin_amdgcn_mfma_f32_16x16x32_bf16(qf[2 * kk + 1], kf1, s_b, 0, 0, 0);
    }
    f32x4 sv = s_a + s_b;

    // ---- no-max softmax ----
#pragma unroll
    for (int r = 0; r < 4; ++r) {
      float p = exp2f(sv[r] * SCL2);
      lsum[r] += p;
      Pl[(a * 16 + quad * 4 + r) * 40 + h * 16 + l16] = (short)f2bf(p);
    }

    __syncthreads();   // B1: V loads drained; Kt reads done; P visible

    // ---- stage K tile kt+1 (readers finished at B1) ----
    if (kt + 1 < 64) {
      size_t adv = (size_t)(kt + 1) * 16384;
#pragma unroll
      for (int i = 0; i < 4; ++i)
        ASYNC16(kdma[i] + adv, &Kt[(wv * 4 + i) * 512]);
    }

    // ---- PV: O[64 x 64e-slice] += P[64x32] @ V[32 x 64e] ----
    s16x8 pf[4];
#pragma unroll
    for (int rb = 0; rb < 4; ++rb)
      pf[rb] = *(const s16x8*)(&Pl[(rb * 16 + l16) * 40 + quad * 8]);
#pragma unroll
    for (int cb = 0; cb < 4; ++cb)
#pragma unroll
      for (int rb = 0; rb < 4; ++rb)
        acc[rb][cb] = __builtin_amdgcn_mfma_f32_16x16x32_bf16(pf[rb], vf[cb], acc[rb][cb], 0, 0, 0);

    __syncthreads();   // B2: K-DMA drained; Pl WAR protected
  }

  // ---- epilogue: combine row sums (h halves), divide, store fp32 ----
#pragma unroll
  for (int r = 0; r < 4; ++r) {
    float v = lsum[r];
    v += __shfl_xor(v, 1);
    v += __shfl_xor(v, 2);
    v += __shfl_xor(v, 4);
    v += __shfl_xor(v, 8);
    lsum[r] = v;                    // sum over this wave's 16-key half
  }
  if (h == 0 && l16 == 0) {
#pragma unroll
    for (int r = 0; r < 4; ++r) l_l[a * 16 + quad * 4 + r] = lsum[r];
  }
  __syncthreads();
  if (h == 1 && l16 == 0) {
#pragma unroll
    for (int r = 0; r < 4; ++r) l_l[a * 16 + quad * 4 + r] += lsum[r];
  }
  __syncthreads();

#pragma unroll
  for (int rb = 0; rb < 4; ++rb) {
    f32x4 lv = *(const f32x4*)(l_l + rb * 16 + quad * 4);
    f32x4 li;
#pragma unroll
    for (int r = 0; r < 4; ++r) li[r] = 1.0f / lv[r];
#pragma unroll
    for (int cb = 0; cb < 4; ++cb)
#pragma unroll
      for (int r = 0; r < 4; ++r)
        out[((size_t)b * S_LEN + s0 + rb * 16 + quad * 4 + r) * 512 + e0 + cb * 16 + l16] =
            acc[rb][cb][r] * li[r];
  }
}

// ---------------- host launch ----------------
extern "C" void kernel_launch(void* const* d_in, const int* in_sizes, int n_in,
                              void* d_out, int out_size, void* d_ws, size_t ws_size,
                              hipStream_t stream) {
  const float* x  = (const float*)d_in[0];
  const float* Wq = (const float*)d_in[1];
  const float* bq = (const float*)d_in[2];
  const float* Wk = (const float*)d_in[3];
  const float* bk = (const float*)d_in[4];
  const float* Wv = (const float*)d_in[5];
  const float* bv = (const float*)d_in[6];

  short* Wt  = (short*)d_ws;
  short* xb  = (short*)((char*)d_ws + 1572864);
  short* Qg  = xb + (size_t)8388608;
  short* Kg  = Qg + (size_t)8388608;
  short* VTg = Kg + (size_t)8388608;

  xconv_kernel<<<4096, 256, 0, stream>>>(x, xb);
  wconv_kernel<<<3072, 256, 0, stream>>>(Wq, Wk, Wv, Wt);
  qkv_gemm<<<1536, 256, 0, stream>>>(xb, Wt, bq, bk, bv, Qg, Kg, VTg);
  attn_kernel<<<256, 512, 0, stream>>>(Qg, Kg, VTg, (float*)d_out);
}